// Round 11
// baseline (2017.731 us; speedup 1.0000x reference)
//
#include <hip/hip_runtime.h>
#include <hip/hip_bf16.h>
#include <math.h>

typedef __hip_bfloat16 bf16;
typedef __attribute__((ext_vector_type(8))) short bf16x8;
typedef __attribute__((ext_vector_type(4))) float f32x4;

#define MFMA(a,b,c) __builtin_amdgcn_mfma_f32_16x16x32_bf16(a,b,c,0,0,0)

#define B_ 8
#define C_ 3
#define IMG_ 512
#define P_ 16
#define DIM_ 256
#define HEADS_ 8
#define DEPTH_ 4
#define DH_ 32
#define L_ 1024
#define EC_ 64
#define PD_ 1024
#define NPATCH 8192
#define NROWS 65536

__device__ __forceinline__ float ldsel(const void* p, long i, int m){
    return m ? __bfloat162float(((const bf16*)p)[i]) : ((const float*)p)[i];
}
__device__ __forceinline__ float geluf(float x){
    return 0.5f * x * (1.0f + erff(x * 0.70710678118654752f));
}
__device__ __forceinline__ short f2bf_s(float f){
    bf16 h = __float2bfloat16(f); return *(short*)&h;
}
__device__ __forceinline__ float bfs2f(short s){
    bf16 h = *(bf16*)&s; return __bfloat162float(h);
}
__device__ __forceinline__ void split2(float f, short& hi, short& lo){
    hi = f2bf_s(f);
    lo = f2bf_s(f - bfs2f(hi));
}
__device__ __forceinline__ void split3(float f, short& h, short& m, short& l){
    h = f2bf_s(f); float r1 = f - bfs2f(h);
    m = f2bf_s(r1); float r2 = r1 - bfs2f(m);
    l = f2bf_s(r2);
}

// Runtime input-dtype detection (bf16 vs fp32): exponent-byte histogram.
__global__ void detect_kernel(const void* __restrict__ img, int* __restrict__ flag)
{
    const unsigned* w = (const unsigned*)img;
    int c = 0;
    for (int i = 0; i < 256; i++){
        unsigned b = (w[i] >> 7) & 0xFFu;
        if (b >= 100u && b <= 145u) c++;
    }
    *flag = (c > 180) ? 1 : 0;
}

// ---------------------------------------------------------------------------
// Conv forward: conv(3->64, 3x3, s2, p1) + bias -> cobuf (fp32) + BN partials.
// Zero-padded 18x18 LDS tile: branch-free 27-tap inner loop.
// ---------------------------------------------------------------------------
__global__ void conv_fwd_kernel(const int* __restrict__ fl,
                                const void* __restrict__ img,
                                const void* __restrict__ conv_w,
                                const void* __restrict__ conv_b,
                                float* __restrict__ cobuf,
                                float* __restrict__ psum, float* __restrict__ psq)
{
    const int f = *fl;
    __shared__ float inp[C_][18][18];
    __shared__ float wl[EC_][27];
    __shared__ float red[256][2];
    const int n = blockIdx.x;
    const int t = threadIdx.x;
    const int b = n >> 10, l = n & 1023;
    const int gy = l >> 5, gx = l & 31;
    for (int e = t; e < 972; e += 256) ((float*)inp)[e] = 0.f;
    for (int e = t; e < EC_*27; e += 256) wl[e/27][e%27] = ldsel(conv_w, e, f);
    __syncthreads();
    for (int e = t; e < C_*P_*P_; e += 256) {
        int c = e >> 8, py = (e >> 4) & 15, px = e & 15;
        inp[c][py+1][px+1] = ldsel(img, ((long)(b*C_+c)*IMG_ + gy*P_+py)*IMG_ + gx*P_+px, f);
    }
    __syncthreads();
    const int o = t >> 2, grp = t & 3;
    const float cb = ldsel(conv_b, o, f);
    float co16[16];
    float s = 0.f, sq = 0.f;
    #pragma unroll
    for (int qq = 0; qq < 16; qq++) {
        int pix = grp*16 + qq;
        int oy = pix >> 3, ox = pix & 7;
        float acc = cb;
        #pragma unroll
        for (int c = 0; c < 3; c++)
        #pragma unroll
        for (int ky = 0; ky < 3; ky++)
        #pragma unroll
        for (int kx = 0; kx < 3; kx++)
            acc += inp[c][oy*2+ky][ox*2+kx] * wl[o][c*9+ky*3+kx];
        co16[qq] = acc;
        s += acc; sq += acc*acc;
    }
    float* cbp = cobuf + (long)n*4096 + o*64 + grp*16;
    #pragma unroll
    for (int i = 0; i < 4; i++)
        *(float4*)(cbp + i*4) = make_float4(co16[i*4], co16[i*4+1], co16[i*4+2], co16[i*4+3]);
    red[t][0] = s; red[t][1] = sq;
    __syncthreads();
    if (t < 64) {
        float S = 0.f, Q = 0.f;
        for (int g = 0; g < 4; g++){ S += red[t*4+g][0]; Q += red[t*4+g][1]; }
        psum[(long)t*NPATCH + n] = S;
        psq [(long)t*NPATCH + n] = Q;
    }
}

__global__ void bn_stats_kernel(const int* __restrict__ fl,
                                const float* __restrict__ psum, const float* __restrict__ psq,
                                const void* __restrict__ bn_g, const void* __restrict__ bn_b,
                                float* __restrict__ scaleA, float* __restrict__ biasA)
{
    const int f = *fl;
    __shared__ float rs[256], rq[256];
    const int o = blockIdx.x, t = threadIdx.x;
    float S = 0.f, Q = 0.f;
    for (int n = t; n < NPATCH; n += 256){ S += psum[(long)o*NPATCH+n]; Q += psq[(long)o*NPATCH+n]; }
    rs[t] = S; rq[t] = Q; __syncthreads();
    for (int st = 128; st > 0; st >>= 1){
        if (t < st){ rs[t] += rs[t+st]; rq[t] += rq[t+st]; }
        __syncthreads();
    }
    if (t == 0){
        const float Ninv = 1.0f / (float)((long)NPATCH * 64);
        float mean = rs[0] * Ninv;
        float var  = rq[0] * Ninv - mean*mean;
        float rstd = rsqrtf(var + 1e-5f);
        float sc = ldsel(bn_g, o, f) * rstd;
        scaleA[o] = sc;
        biasA[o]  = ldsel(bn_b, o, f) - mean*sc;
    }
}

// BN + exact GELU + maxpool(3x3,s2,p1) 8x8->4x4; emits x0 as 3-term splits.
__global__ void bn_gelu_pool_kernel(const float* __restrict__ cobuf,
                                    const float* __restrict__ scaleA,
                                    const float* __restrict__ biasA,
                                    short* __restrict__ x0h, short* __restrict__ x0m,
                                    short* __restrict__ x0l)
{
    __shared__ float cos[64][67];
    __shared__ float sA[64], bA[64];
    const int n = blockIdx.x, t = threadIdx.x;
    if (t < 64){ sA[t] = scaleA[t]; bA[t] = biasA[t]; }
    __syncthreads();
    const float* cb = cobuf + (long)n*4096;
    for (int e = t; e < 4096; e += 256){
        int o = e >> 6, pix = e & 63;
        cos[o][pix] = geluf(cb[e]*sA[o] + bA[o]);
    }
    __syncthreads();
    for (int e = t; e < 1024; e += 256){
        int oo = e >> 4, pp = e & 15;
        int py = pp >> 2, px = pp & 3;
        int y0 = max(0, 2*py-1), y1 = min(7, 2*py+1);
        int xs = max(0, 2*px-1), x1 = min(7, 2*px+1);
        float mx = -INFINITY;
        for (int y = y0; y <= y1; y++)
            for (int x = xs; x <= x1; x++)
                mx = fmaxf(mx, cos[oo][y*8+x]);
        short h, m, l; split3(mx, h, m, l);
        long idx = (long)n*PD_ + e;
        x0h[idx] = h; x0m[idx] = m; x0l[idx] = l;
    }
}

// Elementwise 3-term split (adjacency).
__global__ void split_adj_kernel(const int* __restrict__ fl, const void* __restrict__ adj,
                                 short* __restrict__ Ah, short* __restrict__ Am,
                                 short* __restrict__ Al)
{
    const int f = *fl;
    long i = (long)blockIdx.x*256 + threadIdx.x;
    short h, m, l; split3(ldsel(adj, i, f), h, m, l);
    Ah[i] = h; Am[i] = m; Al[i] = l;
}

// Transpose + 3-term split: out[c][r] = src[r][c].  grid (C/64, R/64).
__global__ void tsplit_kernel(const int* __restrict__ fl, const void* __restrict__ src,
                              long soff, int R, int Ccols,
                              short* __restrict__ oh, short* __restrict__ om,
                              short* __restrict__ ol)
{
    __shared__ float tile[64][65];
    const int f = *fl;
    const int t = threadIdx.x;
    const int c0 = blockIdx.x*64, r0 = blockIdx.y*64;
    for (int e = t; e < 4096; e += 256){
        int r = e >> 6, c = e & 63;
        tile[r][c] = ldsel(src, soff + (long)(r0+r)*Ccols + c0+c, f);
    }
    __syncthreads();
    const int ch = t >> 2, lg = t & 3;
    long ob = (long)(c0+ch)*R + r0 + lg*16;
    bf16x8 h0,h1,m0,m1,l0,l1;
    #pragma unroll
    for (int i = 0; i < 8; i++){
        short h,m,l;
        split3(tile[lg*16+i][ch], h,m,l);    h0[i]=h; m0[i]=m; l0[i]=l;
        split3(tile[lg*16+8+i][ch], h,m,l);  h1[i]=h; m1[i]=m; l1[i]=l;
    }
    *(bf16x8*)(oh+ob) = h0; *(bf16x8*)(oh+ob+8) = h1;
    *(bf16x8*)(om+ob) = m0; *(bf16x8*)(om+ob+8) = m1;
    *(bf16x8*)(ol+ob) = l0; *(bf16x8*)(ol+ob+8) = l1;
}

// Repack xn (b,L,256) fp32 -> xT (b,256,L) 3-term splits.
__global__ void repack_kernel(const float* __restrict__ xn,
                              short* __restrict__ xTh, short* __restrict__ xTm,
                              short* __restrict__ xTl)
{
    __shared__ float tile[64][65];
    const int t = threadIdx.x;
    const int b = blockIdx.z, l0 = blockIdx.y*64, c0 = blockIdx.x*64;
    for (int e = t; e < 4096; e += 256){
        int l = e >> 6, c = e & 63;
        tile[l][c] = xn[((long)(b*L_) + l0 + l)*DIM_ + c0 + c];
    }
    __syncthreads();
    const int ch = t >> 2, lg = t & 3;
    long ob = ((long)(b*DIM_) + c0 + ch)*L_ + l0 + lg*16;
    bf16x8 h0,h1,m0,m1,l0v,l1v;
    #pragma unroll
    for (int i = 0; i < 8; i++){
        short h,m,l;
        split3(tile[lg*16+i][ch], h,m,l);    h0[i]=h; m0[i]=m; l0v[i]=l;
        split3(tile[lg*16+8+i][ch], h,m,l);  h1[i]=h; m1[i]=m; l1v[i]=l;
    }
    *(bf16x8*)(xTh+ob) = h0; *(bf16x8*)(xTh+ob+8) = h1;
    *(bf16x8*)(xTm+ob) = m0; *(bf16x8*)(xTm+ob+8) = m1;
    *(bf16x8*)(xTl+ob) = l0v; *(bf16x8*)(xTl+ob+8) = l1v;
}

// ---------------------------------------------------------------------------
// Generic MFMA GEMM, fp32-accurate via 3-term bf16 splits (6 products).
// C[z] = A[z] @ B[z]^T (+bias) (+D[z]).  A: M×K row-major splits; B: N×K.
// ---------------------------------------------------------------------------
__global__ __launch_bounds__(256)
void mfma_gemm(const short* __restrict__ Ah, const short* __restrict__ Am,
               const short* __restrict__ Al, long strAb,
               const short* __restrict__ Bh, const short* __restrict__ Bm,
               const short* __restrict__ Bl, long strBb,
               const void* __restrict__ bias, long biasOff, const int* __restrict__ fl,
               const float* __restrict__ Dadd, long strDb,
               float* __restrict__ C, long strCb,
               int N, int K)
{
    const int t = threadIdx.x;
    const int w = t >> 6, lane = t & 63;
    const int mrow = lane & 15, quad = lane >> 4;
    const int s0 = blockIdx.y*64 + w*16;
    const int n0 = blockIdx.x*128;
    const int z = blockIdx.z;
    const short* Ahp = Ah + (long)z*strAb;
    const short* Amp = Am + (long)z*strAb;
    const short* Alp = Al + (long)z*strAb;
    const short* Bhp = Bh + (long)z*strBb;
    const short* Bmp = Bm + (long)z*strBb;
    const short* Blp = Bl + (long)z*strBb;
    f32x4 acc[8];
    #pragma unroll
    for (int i = 0; i < 8; i++) acc[i] = (f32x4){0.f,0.f,0.f,0.f};
    for (int k0 = 0; k0 < K; k0 += 32){
        long aoff = (long)(s0 + mrow)*K + k0 + quad*8;
        bf16x8 ah = *(const bf16x8*)(Ahp + aoff);
        bf16x8 am = *(const bf16x8*)(Amp + aoff);
        bf16x8 al = *(const bf16x8*)(Alp + aoff);
        #pragma unroll
        for (int nt = 0; nt < 8; nt++){
            long boff = (long)(n0 + nt*16 + mrow)*K + k0 + quad*8;
            bf16x8 bh = *(const bf16x8*)(Bhp + boff);
            bf16x8 bm = *(const bf16x8*)(Bmp + boff);
            bf16x8 bl = *(const bf16x8*)(Blp + boff);
            acc[nt] = MFMA(al, bh, acc[nt]);
            acc[nt] = MFMA(am, bm, acc[nt]);
            acc[nt] = MFMA(ah, bl, acc[nt]);
            acc[nt] = MFMA(am, bh, acc[nt]);
            acc[nt] = MFMA(ah, bm, acc[nt]);
            acc[nt] = MFMA(ah, bh, acc[nt]);
        }
    }
    const int f = *fl;
    #pragma unroll
    for (int nt = 0; nt < 8; nt++)
    #pragma unroll
    for (int r = 0; r < 4; r++){
        long row = s0 + quad*4 + r;
        int col = n0 + nt*16 + mrow;
        float v = acc[nt][r];
        if (bias) v += ldsel(bias, biasOff + col, f);
        if (Dadd) v += Dadd[(long)z*strDb + row*N + col];
        C[(long)z*strCb + row*N + col] = v;
    }
}

// LayerNorm over last dim (256): shuffle reduction.
__global__ void ln_kernel(const int* __restrict__ fl,
                          const float* __restrict__ x,
                          const void* __restrict__ g, long goff,
                          const void* __restrict__ beta, long boff,
                          float* __restrict__ xn)
{
    const int f = *fl;
    __shared__ float ps[4], pq[4];
    const int r = blockIdx.x, t = threadIdx.x;
    const int w = t >> 6, lane = t & 63;
    float v = x[(long)r*DIM_ + t];
    float s = v, q2 = v*v;
    #pragma unroll
    for (int o = 32; o > 0; o >>= 1){
        s  += __shfl_xor(s, o, 64);
        q2 += __shfl_xor(q2, o, 64);
    }
    if (lane == 0){ ps[w] = s; pq[w] = q2; }
    __syncthreads();
    float S = ps[0]+ps[1]+ps[2]+ps[3];
    float Q = pq[0]+pq[1]+pq[2]+pq[3];
    float mean = S * (1.0f/256.0f);
    float var  = Q * (1.0f/256.0f) - mean*mean;
    float rstd = rsqrtf(var + 1e-5f);
    xn[(long)r*DIM_ + t] = (v - mean)*rstd*ldsel(g, goff + t, f) + ldsel(beta, boff + t, f);
}

// qk = relu(m_head @ qk_w + qk_b). Non-last: 3-term splits. Last: raw fp32.
__global__ void qk_kernel(const int* __restrict__ fl,
                          const float* __restrict__ m_full,
                          const void* __restrict__ qk_w, long woff,
                          const void* __restrict__ qk_b, long boff,
                          short* __restrict__ qh, short* __restrict__ qm, short* __restrict__ ql,
                          short* __restrict__ kh, short* __restrict__ km, short* __restrict__ kl,
                          float* __restrict__ qf, float* __restrict__ kf)
{
    const int f = *fl;
    __shared__ float wl[32][64];
    __shared__ float bl[64];
    __shared__ float mr[16][33];
    const int t = threadIdx.x;
    const int r0 = blockIdx.x * 16;
    const int bh = r0 >> 10, l0 = r0 & 1023;
    const int b = bh >> 3, h = bh & 7;
    for (int e = t; e < 2048; e += 256) wl[e>>6][e&63] = ldsel(qk_w, woff + e, f);
    if (t < 64) bl[t] = ldsel(qk_b, boff + t, f);
    #pragma unroll
    for (int e = t; e < 512; e += 256){
        int r = e >> 5, d = e & 31;
        mr[r][d] = m_full[((long)(b*L_ + l0 + r))*DIM_ + h*DH_ + d];
    }
    __syncthreads();
    const int j = t & 63, rg = t >> 6;
    float acc[4] = {bl[j], bl[j], bl[j], bl[j]};
    #pragma unroll
    for (int d = 0; d < 32; d++){
        float wv = wl[d][j];
        #pragma unroll
        for (int i = 0; i < 4; i++) acc[i] += mr[rg*4+i][d] * wv;
    }
    #pragma unroll
    for (int i = 0; i < 4; i++){
        float a = fmaxf(acc[i], 0.f);
        long r = (long)(bh*L_) + l0 + rg*4 + i;
        if (qf){
            if (j < 32) qf[r*DH_ + j] = a;
            else        kf[r*DH_ + (j-32)] = a;
        } else {
            short hh, mm, ll; split3(a, hh, mm, ll);
            if (j < 32){ qh[r*DH_+j]=hh; qm[r*DH_+j]=mm; ql[r*DH_+j]=ll; }
            else { int d = j-32; kh[r*DH_+d]=hh; km[r*DH_+d]=mm; kl[r*DH_+d]=ll; }
        }
    }
}

// ---------------------------------------------------------------------------
// MFMA attention, 2-pass. Pass A: 3-MFMA approx scores (hh+hm+mh, relative
// error ~2^-15) -> m~ = approx row max, used UN-inflated: exp-arg offset is
// within +-s_max*2^-15/32 (~1 even at s=1e6), so p in [0, e], lsum >= ~0.4 —
// no under/overflow possible, and the constant shift cancels exactly in the
// normalization. (Round 10's inflated certified bound shifted args by
// s_max/1024 and underflowed lsum to 0 -> NaN.)
// Pass B: exact 6-MFMA scores, exp, lsum (+ PV). Pass C (last layer):
// recompute, write normalized probs.
// ---------------------------------------------------------------------------
__global__ __launch_bounds__(256)
void attn_mfma_kernel(const short* __restrict__ qh3, const short* __restrict__ qm3,
                      const short* __restrict__ ql3,
                      const short* __restrict__ kh3, const short* __restrict__ km3,
                      const short* __restrict__ kl3,
                      const float* __restrict__ qf, const float* __restrict__ kf,
                      const short* __restrict__ xTh, const short* __restrict__ xTm,
                      const float* __restrict__ xn,
                      float* __restrict__ mv, float* __restrict__ attn_out)
{
    __shared__ float pt[4][16][37];
    const int t = threadIdx.x;
    const int w = t >> 6, lane = t & 63;
    const int mrow = lane & 15, quad = lane >> 4;
    const int bh = blockIdx.y, b = bh >> 3, h = bh & 7;
    const int s0 = blockIdx.x*64 + w*16;
    const bool last = (attn_out != nullptr);
    const float inv32 = 1.0f/32.0f;
    const long kb = (long)bh*L_*DH_;

    bf16x8 a_h, a_m, a_l;
    {
        long qoff = ((long)bh*L_ + s0 + mrow)*DH_ + quad*8;
        if (last){
            const float* qp = qf + qoff;
            #pragma unroll
            for (int j = 0; j < 8; j++){
                short hh, mm, ll; split3(qp[j], hh, mm, ll);
                a_h[j]=hh; a_m[j]=mm; a_l[j]=ll;
            }
        } else {
            a_h = *(const bf16x8*)(qh3 + qoff);
            a_m = *(const bf16x8*)(qm3 + qoff);
            a_l = *(const bf16x8*)(ql3 + qoff);
        }
    }

    // ---- pass A: approx row max (3 MFMA: hh + hm + mh) ----
    float mmax[4] = {0.f, 0.f, 0.f, 0.f};   // scores >= 0
    for (int ct = 0; ct < 64; ct++){
        long koff = kb + (long)(ct*16 + mrow)*DH_ + quad*8;
        bf16x8 b_h, b_m;
        if (last){
            const float* kp = kf + koff;
            #pragma unroll
            for (int j = 0; j < 8; j++){
                short hh, mm; split2(kp[j], hh, mm);
                b_h[j] = hh; b_m[j] = mm;
            }
        } else {
            b_h = *(const bf16x8*)(kh3 + koff);
            b_m = *(const bf16x8*)(km3 + koff);
        }
        f32x4 a = (f32x4){0.f,0.f,0.f,0.f};
        a = MFMA(a_h, b_h, a);
        a = MFMA(a_h, b_m, a);
        a = MFMA(a_m, b_h, a);
        #pragma unroll
        for (int r = 0; r < 4; r++) mmax[r] = fmaxf(mmax[r], a[r]);
    }
    #pragma unroll
    for (int r = 0; r < 4; r++){
        #pragma unroll
        for (int o = 1; o <= 8; o <<= 1)
            mmax[r] = fmaxf(mmax[r], __shfl_xor(mmax[r], o, 64));
    }

    // ---- pass B: exact scores, exp, lsum (+ PV for non-last) ----
    float lsum[4] = {0.f,0.f,0.f,0.f};
    f32x4 pv[2];
    pv[0] = (f32x4){0.f,0.f,0.f,0.f};
    pv[1] = (f32x4){0.f,0.f,0.f,0.f};
    for (int pr = 0; pr < 32; pr++){
        #pragma unroll
        for (int u = 0; u < 2; u++){
            int ct = pr*2 + u;
            long koff = kb + (long)(ct*16 + mrow)*DH_ + quad*8;
            bf16x8 b_h, b_m, b_l;
            if (last){
                const float* kp = kf + koff;
                #pragma unroll
                for (int j = 0; j < 8; j++){
                    short hh, mm, ll; split3(kp[j], hh, mm, ll);
                    b_h[j]=hh; b_m[j]=mm; b_l[j]=ll;
                }
            } else {
                b_h = *(const bf16x8*)(kh3 + koff);
                b_m = *(const bf16x8*)(km3 + koff);
                b_l = *(const bf16x8*)(kl3 + koff);
            }
            f32x4 a = (f32x4){0.f,0.f,0.f,0.f};
            a = MFMA(a_l, b_h, a);
            a = MFMA(a_m, b_m, a);
            a = MFMA(a_h, b_l, a);
            a = MFMA(a_m, b_h, a);
            a = MFMA(a_h, b_m, a);
            a = MFMA(a_h, b_h, a);
            #pragma unroll
            for (int r = 0; r < 4; r++){
                float p = __expf((a[r] - mmax[r]) * inv32);
                lsum[r] += p;
                if (!last) pt[w][quad*4 + r][u*16 + mrow] = p;
            }
        }
        if (!last){
            // per-wave LDS tile: same-wave write->read ordered by lgkmcnt
            const float* pp = &pt[w][mrow][quad*8];
            bf16x8 phi, plo;
            #pragma unroll
            for (int jj = 0; jj < 8; jj++){
                short hh, ll; split2(pp[jj], hh, ll);
                phi[jj] = hh; plo[jj] = ll;
            }
            int j0 = pr*32;
            #pragma unroll
            for (int nt = 0; nt < 2; nt++){
                long xoff = ((long)(b*DIM_) + h*DH_ + nt*16 + mrow)*L_ + j0 + quad*8;
                bf16x8 xh8 = *(const bf16x8*)(xTh + xoff);
                bf16x8 xl8 = *(const bf16x8*)(xTm + xoff);
                pv[nt] = MFMA(plo, xh8, pv[nt]);
                pv[nt] = MFMA(phi, xl8, pv[nt]);
                pv[nt] = MFMA(phi, xh8, pv[nt]);
            }
        }
    }
    #pragma unroll
    for (int r = 0; r < 4; r++){
        lsum[r] += __shfl_xor(lsum[r], 1, 64);
        lsum[r] += __shfl_xor(lsum[r], 2, 64);
        lsum[r] += __shfl_xor(lsum[r], 4, 64);
        lsum[r] += __shfl_xor(lsum[r], 8, 64);
    }
    float linv[4];
    #pragma unroll
    for (int r = 0; r < 4; r++) linv[r] = 1.0f / lsum[r];

    if (!last){
        #pragma unroll
        for (int nt = 0; nt < 2; nt++)
        #pragma unroll
        for (int r = 0; r < 4; r++){
            long row = s0 + quad*4 + r;
            int d = nt*16 + mrow;
            float resid = xn[((long)(b*L_) + row)*DIM_ + h*DH_ + d];
            mv[((long)bh*L_ + row)*DH_ + d] = pv[nt][r]*linv[r] + resid;
        }
    } else {
        // ---- pass C: recompute scores, write normalized probs ----
        for (int ct = 0; ct < 64; ct++){
            long koff = kb + (long)(ct*16 + mrow)*DH_ + quad*8;
            const float* kp = kf + koff;
            bf16x8 b_h, b_m, b_l;
            #pragma unroll
            for (int j = 0; j < 8; j++){
                short hh, mm, ll; split3(kp[j], hh, mm, ll);
                b_h[j]=hh; b_m[j]=mm; b_l[j]=ll;
            }
            f32x4 a = (f32x4){0.f,0.f,0.f,0.f};
            a = MFMA(a_l, b_h, a);
            a = MFMA(a_m, b_m, a);
            a = MFMA(a_h, b_l, a);
            a = MFMA(a_m, b_h, a);
            a = MFMA(a_h, b_m, a);
            a = MFMA(a_h, b_h, a);
            #pragma unroll
            for (int r = 0; r < 4; r++){
                float pn = __expf((a[r] - mmax[r]) * inv32) * linv[r];
                attn_out[((long)bh*L_ + s0 + quad*4 + r)*L_ + ct*16 + mrow] = pn;
            }
        }
    }
}

// v2 = gelu(relu(mv @ v_w + v_b)); emits 3-term splits, row-major (b*L, 256).
__global__ void v_kernel(const int* __restrict__ fl,
                         const float* __restrict__ mv,
                         const void* __restrict__ v_w, long woff,
                         const void* __restrict__ v_b, long boff,
                         short* __restrict__ v2h, short* __restrict__ v2m,
                         short* __restrict__ v2l)
{
    const int f = *fl;
    __shared__ float wl[32][33];
    __shared__ float bl[32];
    __shared__ float mr[32][33];
    const int t = threadIdx.x;
    const int r0 = blockIdx.x * 32;
    for (int e = t; e < 1024; e += 256) wl[e>>5][e&31] = ldsel(v_w, woff + e, f);
    if (t < 32) bl[t] = ldsel(v_b, boff + t, f);
    #pragma unroll
    for (int e = t; e < 1024; e += 256){
        int r = e >> 5, d = e & 31;
        mr[r][d] = mv[(long)(r0+r)*DH_ + d];
    }
    __syncthreads();
    const int j = t & 31, rg = t >> 5;
    float acc[4] = {bl[j], bl[j], bl[j], bl[j]};
    #pragma unroll
    for (int d = 0; d < 32; d++){
        float wv = wl[d][j];
        #pragma unroll
        for (int i = 0; i < 4; i++) acc[i] += mr[rg*4+i][d] * wv;
    }
    #pragma unroll
    for (int i = 0; i < 4; i++){
        float a = geluf(fmaxf(acc[i], 0.f));
        int r = r0 + rg*4 + i;
        int bh = r >> 10, l = r & 1023;
        int b = bh >> 3, h = bh & 7;
        long idx = ((long)(b*L_) + l)*DIM_ + h*DH_ + j;
        short hh, mm, ll; split3(a, hh, mm, ll);
        v2h[idx] = hh; v2m[idx] = mm; v2l[idx] = ll;
    }
}

extern "C" void kernel_launch(void* const* d_in, const int* in_sizes, int n_in,
                              void* d_out, int out_size, void* d_ws, size_t ws_size,
                              hipStream_t stream)
{
    const int o = (n_in >= 16) ? 3 : 2;
    const void* img    = d_in[0];
    const void* adj    = d_in[1];
    const void* conv_w = d_in[o+0];
    const void* conv_b = d_in[o+1];
    const void* bn_g   = d_in[o+2];
    const void* bn_b   = d_in[o+3];
    const void* emb_w  = d_in[o+4];
    const void* emb_b  = d_in[o+5];
    const void* ln_g   = d_in[o+6];
    const void* ln_b   = d_in[o+7];
    const void* qk_w   = d_in[o+8];
    const void* qk_b   = d_in[o+9];
    const void* v_w    = d_in[o+10];
    const void* v_b    = d_in[o+11];
    const void* proj_w = d_in[o+12];
    float* attn_out = (float*)d_out;   // reference output dtype = float32

    // d_out scratch (64M floats). Lifetimes: pre-loop {cobuf,x0,psum,embT},
    // loop {xn,mfull,xT,q3,k3,v2,pT}. Final attn reads only d_ws, writes all.
    float* S = (float*)d_out;
    const long M1 = 1L << 20;
    float* x     = S;                      // 0..2M (permanent)
    float* xn    = S + 2*M1;               // 2..4M (loop)
    float* mfull = S + 4*M1;               // 4..6M (loop; aliased mv)
    float* mvb   = mfull;
    short* sp    = (short*)(S + 6*M1);     // permanent shorts: adj splits, embT
    short* adjh  = sp;
    short* adjm  = sp + 1*M1;
    short* adjl  = sp + 2*M1;
    short* embTh = sp + 3*M1;              // 256K each (pre-loop)
    short* embTm = embTh + 262144;
    short* embTl = embTm + 262144;
    short* lp    = (short*)(S + 8*M1);     // loop shorts pool (floats 8..20.1M)
    short* xTh   = lp;                     // 2M shorts each
    short* xTm   = lp + 2*M1;
    short* xTl   = lp + 4*M1;
    short* qh3   = lp + 6*M1;
    short* qm3   = lp + 8*M1;
    short* ql3   = lp + 10*M1;
    short* kh3   = lp + 12*M1;
    short* km3   = lp + 14*M1;
    short* kl3   = lp + 16*M1;
    short* v2h   = lp + 18*M1;
    short* v2m   = lp + 20*M1;
    short* v2l   = lp + 22*M1;
    short* pTh   = lp + 24*M1;             // 64K each
    short* pTm   = pTh + 65536;
    short* pTl   = pTm + 65536;
    float* psum  = S + 8*M1;               // pre-loop only (overlaps loop pool)
    float* psq   = psum + (long)EC_*NPATCH;
    float* cobuf = S + 9*M1;               // 9..41M (pre-loop)
    short* x0h   = (short*)(S + 41*M1);    // 8M shorts each -> floats 41..53M
    short* x0m   = x0h + 8*M1;
    short* x0l   = x0m + 8*M1;

    float* wsf   = (float*)d_ws;           // ws use: 16 MB + 1 KB (proven size)
    int*   flag  = (int*)wsf;
    float* scaleA= wsf + 64;
    float* biasA = wsf + 128;
    float* qF    = wsf + 256;              // 2M floats (final-layer q, fp32)
    float* kF    = qF + 2*M1;              // 2M floats

    detect_kernel<<<1, 1, 0, stream>>>(img, flag);
    split_adj_kernel<<<L_*L_/256, 256, 0, stream>>>(flag, adj, adjh, adjm, adjl);
    tsplit_kernel<<<dim3(4,16), 256, 0, stream>>>(flag, emb_w, 0, PD_, DIM_, embTh, embTm, embTl);
    conv_fwd_kernel<<<NPATCH, 256, 0, stream>>>(flag, img, conv_w, conv_b, cobuf, psum, psq);
    bn_stats_kernel<<<EC_, 256, 0, stream>>>(flag, psum, psq, bn_g, bn_b, scaleA, biasA);
    bn_gelu_pool_kernel<<<NPATCH, 256, 0, stream>>>(cobuf, scaleA, biasA, x0h, x0m, x0l);

    // x = x0 @ emb_w + emb_b   (8192x1024 @ 1024x256) via MFMA splits
    mfma_gemm<<<dim3(2,128,1), 256, 0, stream>>>(
        x0h, x0m, x0l, 0,  embTh, embTm, embTl, 0,
        emb_b, 0, flag,  nullptr, 0,  x, 0,  DIM_, PD_);

    for (int i = 0; i < DEPTH_; i++){
        const bool last = (i == DEPTH_-1);
        ln_kernel<<<NPATCH, 256, 0, stream>>>(flag, x, ln_g, (long)i*DIM_, ln_b, (long)i*DIM_, xn);
        repack_kernel<<<dim3(4,16,8), 256, 0, stream>>>(xn, xTh, xTm, xTl);
        // m = A @ xn + xn  (batched over b)
        mfma_gemm<<<dim3(2,16,8), 256, 0, stream>>>(
            adjh, adjm, adjl, 0,  xTh, xTm, xTl, (long)DIM_*L_,
            nullptr, 0, flag,  xn, (long)L_*DIM_,  mfull, (long)L_*DIM_,  DIM_, L_);
        qk_kernel<<<NROWS/16, 256, 0, stream>>>(flag, mfull,
            qk_w, (long)i*DH_*2*DH_, qk_b, (long)i*2*DH_,
            qh3, qm3, ql3, kh3, km3, kl3,
            last ? qF : nullptr, last ? kF : nullptr);
        attn_mfma_kernel<<<dim3(16, B_*HEADS_), 256, 0, stream>>>(
            qh3, qm3, ql3, kh3, km3, kl3, qF, kF, xTh, xTm, xn,
            last ? nullptr : mvb, last ? attn_out : nullptr);
        if (!last){
            v_kernel<<<NROWS/32, 256, 0, stream>>>(flag, mvb,
                v_w, (long)i*DH_*DH_, v_b, (long)i*DH_, v2h, v2m, v2l);
            tsplit_kernel<<<dim3(4,4), 256, 0, stream>>>(flag, proj_w,
                (long)i*DIM_*DIM_, DIM_, DIM_, pTh, pTm, pTl);
            // x = v2 @ proj_w + xn
            mfma_gemm<<<dim3(2,128,1), 256, 0, stream>>>(
                v2h, v2m, v2l, 0,  pTh, pTm, pTl, 0,
                nullptr, 0, flag,  xn, 0,  x, 0,  DIM_, DIM_);
        }
    }
}